// Round 13
// baseline (223.875 us; speedup 1.0000x reference)
//
#include <hip/hip_runtime.h>
#include <hip/hip_bf16.h>

// CC_module_H: height-axis criss-cross attention. B=8, C=512, C8=64, H=W=96.
// Round 13: r12 + pv rebalanced across ALL 16 waves (96 (i-tile,c-quad) units,
// 6 per wave, 18 MFMA/wave vs 24-on-12-waves) — removes the 25% idle in both
// PV phases. Everything else byte-identical to r12 (165.1us proven).

typedef __attribute__((ext_vector_type(8))) short bh8;   // 8 bf16 = MFMA frag
typedef __attribute__((ext_vector_type(4))) float fx4;   // MFMA 16x16 accum

#define MFMA16(a, b, c) __builtin_amdgcn_mfma_f32_16x16x32_bf16((a), (b), (c), 0, 0, 0)
#define MFMA8(a, b, c) __builtin_amdgcn_mfma_f32_16x16x32_fp8_fp8((a), (b), (c), 0, 0, 0)

__device__ __forceinline__ unsigned short f2bf(float f) {
  unsigned u = __float_as_uint(f);
  u += 0x7fffu + ((u >> 16) & 1u);   // RNE (finite inputs only)
  return (unsigned short)(u >> 16);
}
__device__ __forceinline__ float bf2f(unsigned short u) {
  return __uint_as_float((unsigned)u << 16);
}
// HW packed f32x2 -> bf16x2 (RNE, matches f2bf bit-exact on finite inputs).
__device__ __forceinline__ unsigned cvtpk_bf16(float lo, float hi) {
#if defined(__gfx950__)
  unsigned r;
  asm volatile("v_cvt_pk_bf16_f32 %0, %1, %2" : "=v"(r) : "v"(lo), "v"(hi));
  return r;
#else
  return (unsigned)f2bf(lo) | ((unsigned)f2bf(hi) << 16);
#endif
}
// Software OCP e4m3fn encode (fallback only).
__device__ __forceinline__ unsigned char f2e4m3(float f) {
  unsigned b = __float_as_uint(f);
  unsigned s = (b >> 24) & 0x80u;
  unsigned a = b & 0x7fffffffu;
  float af = __uint_as_float(a);
  if (af >= 448.f) return (unsigned char)(s | 0x7e);
  if (af < 0.015625f) {
    int n = (int)(af * 512.0f + 0.5f);
    return (unsigned char)(s | (unsigned)n);
  }
  a += 0x7ffffu + ((a >> 20) & 1u);
  unsigned E = a >> 23, M = (a >> 20) & 7u;
  if (E >= 136u) return (unsigned char)(s | 0x7e);
  return (unsigned char)(s | ((E - 120u) << 3) | M);
}
#if __has_builtin(__builtin_amdgcn_cvt_pk_fp8_f32)
#define CVTPK8(a, b) __builtin_amdgcn_cvt_pk_fp8_f32((a), (b), 0, false)
#else
#define CVTPK8(a, b) ((int)f2e4m3(a) | ((int)f2e4m3(b) << 8))
#endif

// ---------------- prep: weights fp32 -> bf16, MFMA-A-fragment order in ws ----
__global__ __launch_bounds__(256) void prep_w(const float* __restrict__ Wq,
                                              const float* __restrict__ Wk,
                                              const float* __restrict__ Wv,
                                              short* __restrict__ wf) {
  int tid = blockIdx.x * 256 + threadIdx.x;
  if (tid >= 40960) return;
  int lane = tid & 63;
  int es = (tid >> 6) & 15;
  int gt = tid >> 10;
  int rt = lane & 15;
  int colbase = es * 32 + (lane >> 4) * 8;
  const float* src;
  size_t dst;
  if (gt < 8) {
    int m = gt * 16 + rt;
    src = (m < 64) ? (Wq + (size_t)m * 512) : (Wk + (size_t)(m - 64) * 512);
    dst = (size_t)((gt * 16 + es) * 64 + lane) * 8;
  } else {
    int ct = gt - 8;
    src = Wv + (size_t)(ct * 16 + rt) * 512;
    dst = 65536u + (size_t)((ct * 16 + es) * 64 + lane) * 8;
  }
  bh8 v;
#pragma unroll
  for (int r = 0; r < 8; ++r) v[r] = (short)f2bf(src[colbase + r]);
  *(bh8*)(wf + dst) = v;
}

// ---------------- transpose-in: x[b,c,h,w] f32 -> xT[b,w,h,c] bf16 -----------
__global__ __launch_bounds__(512) void transpose_in(const float* __restrict__ x,
                                                    unsigned short* __restrict__ xT) {
  __shared__ unsigned short L[96 * 132];
  int bi = blockIdx.x;
  int ct = bi & 3;
  int hb = bi >> 2;
  int h = hb % 96;
  int b = hb / 96;
  int tid = threadIdx.x;
  const float* xs = x + ((size_t)(b * 512 + ct * 128) * 96 + h) * 96;
#pragma unroll
  for (int i = 0; i < 12; ++i) {
    int idx = tid + 512 * i;          // 128 cc x 48 w-pairs (float2)
    int cc = idx / 48, wp = idx - cc * 48;
    float2 v = *(const float2*)(xs + (size_t)cc * 9216 + 2 * wp);
    L[(2 * wp) * 132 + cc] = f2bf(v.x);
    L[(2 * wp + 1) * 132 + cc] = f2bf(v.y);
  }
  __syncthreads();
  unsigned short* dst = xT + ((size_t)(b * 96) * 96 + h) * 512 + ct * 128;
#pragma unroll
  for (int i = 0; i < 6; ++i) {
    int idx = tid + 512 * i;          // 96 w x 32 c-quads (8 B)
    int w = idx >> 5, ccq = idx & 31;
    *(ushort4*)(dst + (size_t)w * 49152 + ccq * 4) =
        *(const ushort4*)&L[w * 132 + ccq * 4];
  }
}

// ---------------- un-transpose: out = f32(outT) (residual already folded) ----
__global__ __launch_bounds__(512) void untrans(const unsigned short* __restrict__ oT,
                                               float* __restrict__ out, int b0) {
  __shared__ unsigned short L[128 * 101];
  int bi = blockIdx.x;
  int ct = bi & 3;
  int hb = bi >> 2;
  int h = hb % 96;
  int brel = hb / 96;
  int b = b0 + brel;
  int tid = threadIdx.x;
  const unsigned short* src = oT + ((size_t)(brel * 96) * 96 + h) * 512 + ct * 128;
#pragma unroll
  for (int i = 0; i < 3; ++i) {
    int idx = tid + 512 * i;          // 96 w x 16 c-octs (16 B)
    int w = idx >> 4, ccb = idx & 15;
    bh8 v = *(const bh8*)(src + (size_t)w * 49152 + ccb * 8);
#pragma unroll
    for (int r = 0; r < 8; ++r) L[(ccb * 8 + r) * 101 + w] = (unsigned short)v[r];
  }
  __syncthreads();
  float* os = out + ((size_t)(b * 512 + ct * 128) * 96 + h) * 96;
#pragma unroll
  for (int i = 0; i < 12; ++i) {
    int idx = tid + 512 * i;          // 128 cc x 48 w-pairs (float2 stores)
    int cc = idx / 48, wp = idx - cc * 48;
    float2 v;
    v.x = bf2f(L[cc * 101 + 2 * wp]);
    v.y = bf2f(L[cc * 101 + 2 * wp + 1]);
    *(float2*)(os + (size_t)cc * 9216 + 2 * wp) = v;
  }
}

// ---------------- main fused kernel (round 13): one wg per (b,w) -------------
// LDS map (bytes), 157440 total — 1024 threads (16 waves, 4 waves/SIMD):
//   X    [96][512] bf16, pitch 1024, XOR swizzle byte^=((j&7)<<4)  0      .. 98304
//   Q    [96][64]  bf16, pitch 128, XOR swizzle                    98304  .. 110592
//   K    [96][64]  bf16, pitch 128, XOR swizzle                    110592 .. 122880
//   ATT8 [96][104] fp8                                             122880 .. 132864
//   V8A  [256][96] fp8, row-XOR swizzle ((row>>2)&3)<<3            132864 .. 157440
//   V8B  [256][96] fp8 — aliases Q/K (dead after softmax)          98304  .. 122880
// X stays live to the end (residual source for the epilogue).
#define XO5 0
#define QO5 98304
#define KO5 110592
#define AT5 122880
#define V5A 132864
#define V5B 98304
#define SMEM5 157440

__global__ __launch_bounds__(1024, 4) void cc_fused12(
    const float* __restrict__ bq, const float* __restrict__ bk,
    const float* __restrict__ bv, const float* __restrict__ gamma,
    const short* __restrict__ wf, const unsigned short* __restrict__ xT,
    unsigned short* __restrict__ outTm, unsigned short* __restrict__ outT7) {
  extern __shared__ char smem[];
  const int tid = threadIdx.x;
  const int l = tid & 63, wv = tid >> 6;          // wv in [0,16)
  const int rl = l & 15, kg = l >> 4;
  const int bid = blockIdx.x;
  const float g0 = gamma[0];
  const unsigned short* xrow = xT + (size_t)bid * 49152;
  const short* wvb = wf + 65536;

  unsigned short* obase = (bid < 672)
      ? (outTm + (size_t)bid * 49152)
      : (outT7 + (size_t)(bid - 672) * 49152);

  // ---- vblk4: 256-ch block cb -> V8 fp8; 4mt x 3nt; es=0 frags preloaded ----
  auto vblk4 = [&](int cb, int vo, int mg4, int ng4, bh8 c0, bh8 c1, bh8 c2, bh8 c3) {
    const int mtb = mg4 * 4;
    fx4 vac[4][3] = {};
    bh8 ac[4] = {c0, c1, c2, c3};
#pragma unroll 2
    for (int es = 0; es < 16; ++es) {
      int esn = (es < 15) ? es + 1 : 15;
      bh8 an[4];
#pragma unroll
      for (int q = 0; q < 4; ++q)
        an[q] = *(const bh8*)(wvb + (((cb * 16 + mtb + q) * 16 + esn) * 64 + l) * 8);
      int kb = es * 64 + kg * 16;
      __builtin_amdgcn_s_setprio(1);
#pragma unroll
      for (int t = 0; t < 3; ++t) {
        int j = (3 * ng4 + t) * 16 + rl;
        bh8 bx = *(const bh8*)(smem + XO5 + j * 1024 + (kb ^ ((j & 7) << 4)));
#pragma unroll
        for (int q = 0; q < 4; ++q) vac[q][t] = MFMA16(ac[q], bx, vac[q][t]);
      }
      __builtin_amdgcn_s_setprio(0);
#pragma unroll
      for (int q = 0; q < 4; ++q) ac[q] = an[q];
    }
#pragma unroll
    for (int q = 0; q < 4; ++q)
#pragma unroll
      for (int r = 0; r < 4; ++r) {
        int row = (mtb + q) * 16 + kg * 4 + r;
        int sz = ((row >> 2) & 3) << 3;
        int a = row * 96 + ng4 * 48 + rl;
        unsigned char* vp = (unsigned char*)smem + vo;
        int p01 = CVTPK8(vac[q][0][r], vac[q][1][r]);
        int p22 = CVTPK8(vac[q][2][r], vac[q][2][r]);
        vp[a ^ sz] = (unsigned char)p01;
        vp[(a + 16) ^ sz] = (unsigned char)(p01 >> 8);
        vp[(a + 32) ^ sz] = (unsigned char)p22;
      }
  };

  // ---- vblk2: 2mt x 3nt, all 16 waves; es=0 frags preloaded ----
  auto vblk2 = [&](int cb, int vo, bh8 c0, bh8 c1) {
    const int mg = wv >> 1, ng = wv & 1;
    const int mtb = mg * 2;
    fx4 vac[2][3] = {};
    bh8 ac[2] = {c0, c1};
#pragma unroll 2
    for (int es = 0; es < 16; ++es) {
      int esn = (es < 15) ? es + 1 : 15;
      bh8 an[2];
#pragma unroll
      for (int q = 0; q < 2; ++q)
        an[q] = *(const bh8*)(wvb + (((cb * 16 + mtb + q) * 16 + esn) * 64 + l) * 8);
      int kb = es * 64 + kg * 16;
      __builtin_amdgcn_s_setprio(1);
#pragma unroll
      for (int t = 0; t < 3; ++t) {
        int j = (3 * ng + t) * 16 + rl;
        bh8 bx = *(const bh8*)(smem + XO5 + j * 1024 + (kb ^ ((j & 7) << 4)));
        vac[0][t] = MFMA16(ac[0], bx, vac[0][t]);
        vac[1][t] = MFMA16(ac[1], bx, vac[1][t]);
      }
      __builtin_amdgcn_s_setprio(0);
      ac[0] = an[0];
      ac[1] = an[1];
    }
#pragma unroll
    for (int q = 0; q < 2; ++q)
#pragma unroll
      for (int r = 0; r < 4; ++r) {
        int row = (mtb + q) * 16 + kg * 4 + r;
        int sz = ((row >> 2) & 3) << 3;
        int a = row * 96 + ng * 48 + rl;
        unsigned char* vp = (unsigned char*)smem + vo;
        int p01 = CVTPK8(vac[q][0][r], vac[q][1][r]);
        int p22 = CVTPK8(vac[q][2][r], vac[q][2][r]);
        vp[a ^ sz] = (unsigned char)p01;
        vp[(a + 16) ^ sz] = (unsigned char)(p01 >> 8);
        vp[(a + 32) ^ sz] = (unsigned char)p22;
      }
  };

  // ---- pv16: ALL 16 waves; 96 units = 6 i-tiles x 16 c-quads, 6 per wave ----
  auto pv16 = [&](int cb, int vo) {
    fx4 pac[6];
    int itu[6], cqu[6];
#pragma unroll
    for (int u = 0; u < 6; ++u) {
      int ug = wv * 6 + u;
      itu[u] = ug >> 4;
      cqu[u] = ug & 15;
      pac[u] = (fx4){0.f, 0.f, 0.f, 0.f};
    }
    __builtin_amdgcn_s_setprio(1);
#pragma unroll
    for (int ks = 0; ks < 3; ++ks) {
#pragma unroll
      for (int u = 0; u < 6; ++u) {
        long aa = *(const long*)(smem + AT5 + (itu[u] * 16 + rl) * 104 +
                                 ks * 32 + kg * 8);
        int row = cqu[u] * 16 + rl;
        long bb = *(const long*)(smem + vo +
                                 ((row * 96 + ks * 32 + kg * 8) ^ (((row >> 2) & 3) << 3)));
        pac[u] = MFMA8(aa, bb, pac[u]);
      }
    }
    __builtin_amdgcn_s_setprio(0);
#pragma unroll
    for (int u = 0; u < 6; ++u) {
      int c = cb * 256 + cqu[u] * 16 + rl;
      float gb = g0 * bv[c];    // softmax rows sum to 1 -> v-bias adds directly
      const int i0 = itu[u] * 16 + kg * 4;
      float o[4];
#pragma unroll
      for (int r = 0; r < 4; ++r) {
        unsigned short xv = *(const unsigned short*)(
            smem + XO5 + (i0 + r) * 1024 + ((2 * c) ^ (((i0 + r) & 7) << 4)));
        o[r] = fmaf(g0, pac[u][r], gb + bf2f(xv));
      }
      unsigned pk01 = cvtpk_bf16(o[0], o[1]);
      unsigned pk23 = cvtpk_bf16(o[2], o[3]);
      obase[(size_t)(i0 + 0) * 512 + c] = (unsigned short)pk01;
      obase[(size_t)(i0 + 1) * 512 + c] = (unsigned short)(pk01 >> 16);
      obase[(size_t)(i0 + 2) * 512 + c] = (unsigned short)pk23;
      obase[(size_t)(i0 + 3) * 512 + c] = (unsigned short)(pk23 >> 16);
    }
  };

  // ---- P0: X[j][c] into LDS as bf16 (swizzled), coalesced from xT ----
#pragma unroll
  for (int i = 0; i < 6; ++i) {
    int idx = tid + 1024 * i;       // 96 j x 64 16B-chunks
    int j = idx >> 6, cbk = idx & 63;
    bh8 v = *(const bh8*)(xrow + (size_t)j * 512 + cbk * 8);
    *(bh8*)(smem + XO5 + j * 1024 + ((cbk * 16) ^ ((j & 7) << 4))) = v;
  }
  // cross-barrier prefetch: P1's es=0 weight frag (latency hides under barrier)
  const int mgq = wv >> 1, ngq = wv & 1;          // P1 role: mg in [0,8)
  bh8 p1a = *(const bh8*)(wf + ((mgq * 16 + 0) * 64 + l) * 8);
  __syncthreads();

  // ---- P1: [q;k] = [Wq;Wk] @ X, 1mt x 3nt per wave, +1-ahead A prefetch ----
  {
    fx4 acc[3] = {};
    bh8 a0c = p1a;
#pragma unroll 2
    for (int es = 0; es < 16; ++es) {
      int esn = (es < 15) ? es + 1 : 15;
      bh8 a0n = *(const bh8*)(wf + ((mgq * 16 + esn) * 64 + l) * 8);
      int kb = es * 64 + kg * 16;
      __builtin_amdgcn_s_setprio(1);
#pragma unroll
      for (int t = 0; t < 3; ++t) {
        int j = (3 * ngq + t) * 16 + rl;
        bh8 bx = *(const bh8*)(smem + XO5 + j * 1024 + (kb ^ ((j & 7) << 4)));
        acc[t] = MFMA16(a0c, bx, acc[t]);
      }
      __builtin_amdgcn_s_setprio(0);
      a0c = a0n;
    }
    {
      int base = mgq * 16;
      const float* bp = (base < 64) ? bq : bk;
      const int qko = (base < 64) ? QO5 : KO5;
      const int ml0 = (base & 63) + kg * 4;
      float b0 = bp[ml0], b1 = bp[ml0 + 1], b2 = bp[ml0 + 2], b3 = bp[ml0 + 3];
#pragma unroll
      for (int t = 0; t < 3; ++t) {
        int i = (3 * ngq + t) * 16 + rl;
        unsigned pk01 = cvtpk_bf16(acc[t][0] + b0, acc[t][1] + b1);
        unsigned pk23 = cvtpk_bf16(acc[t][2] + b2, acc[t][3] + b3);
        int swz = (i & 7) << 4;
        *(unsigned*)(smem + qko + i * 128 + ((ml0 * 2) ^ swz)) = pk01;
        *(unsigned*)(smem + qko + i * 128 + ((ml0 * 2 + 4) ^ swz)) = pk23;
      }
    }
  }
  // cross-barrier prefetch: vblk0's es=0 frags for waves 8..15
  bh8 h0, h1, h2, h3;
  if (wv >= 8) {
    int mtb = ((wv - 8) >> 1) * 4;
    h0 = *(const bh8*)(wvb + (((mtb + 0) * 16 + 0) * 64 + l) * 8);
    h1 = *(const bh8*)(wvb + (((mtb + 1) * 16 + 0) * 64 + l) * 8);
    h2 = *(const bh8*)(wvb + (((mtb + 2) * 16 + 0) * 64 + l) * 8);
    h3 = *(const bh8*)(wvb + (((mtb + 3) * 16 + 0) * 64 + l) * 8);
  }
  __syncthreads();

  // ---- Phase A: waves 0-5 softmax ONLY || waves 8-15 vblk0 -> V5A ----
  if (wv < 6) {
    const int i0 = wv * 16;
    fx4 e[6] = {};
#pragma unroll
    for (int ks = 0; ks < 2; ++ks) {
      int kb = (ks * 32 + kg * 8) * 2;
      int ia = i0 + rl;
      bh8 aq = *(const bh8*)(smem + QO5 + ia * 128 + (kb ^ ((ia & 7) << 4)));
#pragma unroll
      for (int jt = 0; jt < 6; ++jt) {
        int j = jt * 16 + rl;
        bh8 bkf = *(const bh8*)(smem + KO5 + j * 128 + (kb ^ ((j & 7) << 4)));
        e[jt] = MFMA16(aq, bkf, e[jt]);
      }
    }
#pragma unroll
    for (int r = 0; r < 4; ++r) {
      float mx = e[0][r];
#pragma unroll
      for (int jt = 1; jt < 6; ++jt) mx = fmaxf(mx, e[jt][r]);
      mx = fmaxf(mx, __shfl_xor(mx, 1));
      mx = fmaxf(mx, __shfl_xor(mx, 2));
      mx = fmaxf(mx, __shfl_xor(mx, 4));
      mx = fmaxf(mx, __shfl_xor(mx, 8));
      float pp[6], s = 0.f;
#pragma unroll
      for (int jt = 0; jt < 6; ++jt) { pp[jt] = __expf(e[jt][r] - mx); s += pp[jt]; }
      s += __shfl_xor(s, 1);
      s += __shfl_xor(s, 2);
      s += __shfl_xor(s, 4);
      s += __shfl_xor(s, 8);
      float inv = 1.0f / s;
      int i = i0 + kg * 4 + r;
      unsigned char* arow = (unsigned char*)smem + AT5 + i * 104 + rl;
      int p01 = CVTPK8(pp[0] * inv, pp[1] * inv);
      int p23 = CVTPK8(pp[2] * inv, pp[3] * inv);
      int p45 = CVTPK8(pp[4] * inv, pp[5] * inv);
      arow[0] = (unsigned char)p01;
      arow[16] = (unsigned char)(p01 >> 8);
      arow[32] = (unsigned char)p23;
      arow[48] = (unsigned char)(p23 >> 8);
      arow[64] = (unsigned char)p45;
      arow[80] = (unsigned char)(p45 >> 8);
    }
  } else if (wv >= 8) {
    vblk4(0, V5A, (wv - 8) >> 1, wv & 1, h0, h1, h2, h3);
  }
  // cross-barrier prefetch: vblk1's es=0 frags (all waves)
  bh8 w20, w21;
  {
    int mtb2 = (wv >> 1) * 2;
    w20 = *(const bh8*)(wvb + (((16 + mtb2 + 0) * 16 + 0) * 64 + l) * 8);
    w21 = *(const bh8*)(wvb + (((16 + mtb2 + 1) * 16 + 0) * 64 + l) * 8);
  }
  __syncthreads();

  // ---- Phase B: pv16(0) all waves, then vblk1 -> V5B (all waves) ----
  pv16(0, V5A);
  vblk2(1, V5B, w20, w21);
  __syncthreads();

  // ---- Phase C: pv16(1) all waves ----
  pv16(1, V5B);
}

// ---------------- legacy self-contained fallback (round-1 proven) ------------
__global__ __launch_bounds__(512, 2) void cc_fused_legacy(
    const float* __restrict__ x, const float* __restrict__ bq,
    const float* __restrict__ bk, const float* __restrict__ bv,
    const float* __restrict__ gamma, const short* __restrict__ wf,
    float* __restrict__ out) {
  extern __shared__ char smem[];
  const int tid = threadIdx.x;
  const int l = tid & 63, wv = tid >> 6;
  const int rl = l & 15, kg = l >> 4;
  const int bid = blockIdx.x;
  const int b = (bid >> 3) / 12;
  const int w = (bid & 7) * 12 + ((bid >> 3) % 12);
  const float g0 = gamma[0];
  const float* xb = x + (size_t)b * 4718592 + w;
  for (int idx = tid; idx < 24576; idx += 512) {
    int j = idx >> 8;
    int c = (idx & 255) * 2;
    float a0 = xb[(size_t)c * 9216 + j * 96];
    float a1 = xb[(size_t)(c + 1) * 9216 + j * 96];
    unsigned pk = (unsigned)f2bf(a0) | ((unsigned)f2bf(a1) << 16);
    *(unsigned*)(smem + j * 1024 + ((c * 2) ^ ((j & 7) << 4))) = pk;
  }
  __syncthreads();
  {
    fx4 acc[6] = {};
    for (int es = 0; es < 16; ++es) {
      bh8 a = *(const bh8*)(wf + ((wv * 16 + es) * 64 + l) * 8);
      int kb = (es * 32 + kg * 8) * 2;
#pragma unroll
      for (int nt = 0; nt < 6; ++nt) {
        int j = nt * 16 + rl;
        bh8 bx = *(const bh8*)(smem + j * 1024 + (kb ^ ((j & 7) << 4)));
        acc[nt] = MFMA16(a, bx, acc[nt]);
      }
    }
    const float* bp = (wv < 4) ? bq : bk;
    const int qko = (wv < 4) ? 118272 : 130560;
    const int mb = (wv * 16) & 63;
#pragma unroll
    for (int r = 0; r < 4; ++r) {
      int ml = mb + kg * 4 + r;
      float bias = bp[ml];
#pragma unroll
      for (int nt = 0; nt < 6; ++nt) {
        int i = nt * 16 + rl;
        *(unsigned short*)(smem + qko + i * 128 + ((ml * 2) ^ ((i & 7) << 4))) =
            f2bf(acc[nt][r] + bias);
      }
    }
  }
  __syncthreads();
  if (wv < 6) {
    const int i0 = wv * 16;
    fx4 e[6] = {};
#pragma unroll
    for (int ks = 0; ks < 2; ++ks) {
      int kb = (ks * 32 + kg * 8) * 2;
      int ia = i0 + rl;
      bh8 aq = *(const bh8*)(smem + 118272 + ia * 128 + (kb ^ ((ia & 7) << 4)));
#pragma unroll
      for (int jt = 0; jt < 6; ++jt) {
        int j = jt * 16 + rl;
        bh8 bkf = *(const bh8*)(smem + 130560 + j * 128 + (kb ^ ((j & 7) << 4)));
        e[jt] = MFMA16(aq, bkf, e[jt]);
      }
    }
#pragma unroll
    for (int r = 0; r < 4; ++r) {
      float mx = e[0][r];
#pragma unroll
      for (int jt = 1; jt < 6; ++jt) mx = fmaxf(mx, e[jt][r]);
      mx = fmaxf(mx, __shfl_xor(mx, 1));
      mx = fmaxf(mx, __shfl_xor(mx, 2));
      mx = fmaxf(mx, __shfl_xor(mx, 4));
      mx = fmaxf(mx, __shfl_xor(mx, 8));
      float p[6], s = 0.f;
#pragma unroll
      for (int jt = 0; jt < 6; ++jt) { p[jt] = __expf(e[jt][r] - mx); s += p[jt]; }
      s += __shfl_xor(s, 1);
      s += __shfl_xor(s, 2);
      s += __shfl_xor(s, 4);
      s += __shfl_xor(s, 8);
      float inv = 1.0f / s;
      int i = i0 + kg * 4 + r;
#pragma unroll
      for (int jt = 0; jt < 6; ++jt) {
        int j = jt * 16 + rl;
        *(unsigned short*)(smem + 98304 + i * 208 + 2 * j) = f2bf(p[jt] * inv);
      }
    }
  }
  __syncthreads();
  for (int cb = 0; cb < 8; ++cb) {
    {
      const int mt = wv >> 1, ntb = (wv & 1) * 3;
      fx4 acc[3] = {};
      for (int es = 0; es < 16; ++es) {
        bh8 a = *(const bh8*)(wf + 65536 + (((cb * 4 + mt) * 16 + es) * 64 + l) * 8);
        int kb = (es * 32 + kg * 8) * 2;
#pragma unroll
        for (int t = 0; t < 3; ++t) {
          int j = (ntb + t) * 16 + rl;
          bh8 bx = *(const bh8*)(smem + j * 1024 + (kb ^ ((j & 7) << 4)));
          acc[t] = MFMA16(a, bx, acc[t]);
        }
      }
#pragma unroll
      for (int t = 0; t < 3; ++t) {
        int j = (ntb + t) * 16 + rl;
#pragma unroll
        for (int r = 0; r < 4; ++r) {
          int cl = mt * 16 + kg * 4 + r;
          *(unsigned short*)(smem + 118272 + cl * 208 + 2 * j) = f2bf(acc[t][r]);
        }
      }
    }
    __syncthreads();
    {
      fx4 acc[3] = {};
      const int tg0 = wv * 3;
#pragma unroll
      for (int ks = 0; ks < 3; ++ks) {
        int jb = (ks * 32 + kg * 8) * 2;
#pragma unroll
        for (int s = 0; s < 3; ++s) {
          int it = (tg0 + s) >> 2, ct = (tg0 + s) & 3;
          bh8 a = *(const bh8*)(smem + 98304 + (it * 16 + rl) * 208 + jb);
          bh8 bvv = *(const bh8*)(smem + 118272 + (ct * 16 + rl) * 208 + jb);
          acc[s] = MFMA16(a, bvv, acc[s]);
        }
      }
#pragma unroll
      for (int s = 0; s < 3; ++s) {
        int it = (tg0 + s) >> 2, ct = (tg0 + s) & 3;
        int c = cb * 64 + ct * 16 + rl;
        float bvc = bv[c];
        size_t base = (size_t)(b * 512 + c) * 9216 + w;
#pragma unroll
        for (int r = 0; r < 4; ++r) {
          int i = it * 16 + kg * 4 + r;
          size_t g = base + (size_t)i * 96;
          out[g] = g0 * (acc[s][r] + bvc) + x[g];
        }
      }
    }
    __syncthreads();
  }
}

extern "C" void kernel_launch(void* const* d_in, const int* in_sizes, int n_in,
                              void* d_out, int out_size, void* d_ws, size_t ws_size,
                              hipStream_t stream) {
  const float* x = (const float*)d_in[0];
  const float* Wq = (const float*)d_in[1];
  const float* bq = (const float*)d_in[2];
  const float* Wk = (const float*)d_in[3];
  const float* bk = (const float*)d_in[4];
  const float* Wv = (const float*)d_in[5];
  const float* bv = (const float*)d_in[6];
  const float* gamma = (const float*)d_in[7];
  float* out = (float*)d_out;
  short* wf = (short*)d_ws;                    // 655,360 B weights at ws+0

  prep_w<<<160, 256, 0, stream>>>(Wq, Wk, Wv, wf);

  const size_t WS_SMALL = 1048576u + 9437184u;           // outT(b=7) only in ws
  const size_t WS_BIG = 1048576u + 75497472u;            // ALL of outT in ws

  if (ws_size >= WS_SMALL) {
    unsigned short* xT = (unsigned short*)d_out;         // 75.5 MB, dead after fused

    hipFuncSetAttribute((const void*)cc_fused12,
                        hipFuncAttributeMaxDynamicSharedMemorySize, SMEM5);
    transpose_in<<<3072, 512, 0, stream>>>(x, xT);

    if (ws_size >= WS_BIG) {
      // All of outT in ws: no out/outT overlap, single un-transpose launch.
      unsigned short* outTall = (unsigned short*)((char*)d_ws + 1048576);
      cc_fused12<<<768, 1024, SMEM5, stream>>>(bq, bk, bv, gamma, (const short*)wf,
                                               xT, outTall,
                                               outTall + (size_t)672 * 49152);
      untrans<<<3072, 512, 0, stream>>>(outTall, out, 0);              // b0..7
    } else {
      unsigned short* outTm = (unsigned short*)((char*)d_out + 75497472);  // b0..6
      unsigned short* outT7 = (unsigned short*)((char*)d_ws + 1048576);    // b7
      cc_fused12<<<768, 1024, SMEM5, stream>>>(bq, bk, bv, gamma, (const short*)wf,
                                               xT, outTm, outT7);
      // Ordered un-transpose passes: each launch only overwrites outT regions
      // consumed by the previous launch (range proof per round 2; xT dead).
      untrans<<<1536, 512, 0, stream>>>(outTm, out, 0);                       // b0..3
      untrans<<<768, 512, 0, stream>>>(outTm + (size_t)4 * 4718592, out, 4);  // b4,5
      untrans<<<384, 512, 0, stream>>>(outTm + (size_t)6 * 4718592, out, 6);  // b6
      untrans<<<384, 512, 0, stream>>>(outT7, out, 7);                        // b7
    }
  } else {
    hipFuncSetAttribute((const void*)cc_fused_legacy,
                        hipFuncAttributeMaxDynamicSharedMemorySize, 142848);
    cc_fused_legacy<<<768, 512, 142848, stream>>>(x, bq, bk, bv, gamma,
                                                  (const short*)wf, out);
  }
}

// Round 14
// 164.371 us; speedup vs baseline: 1.3620x; 1.3620x over previous
//
#include <hip/hip_runtime.h>
#include <hip/hip_bf16.h>

// CC_module_H: height-axis criss-cross attention. B=8, C=512, C8=64, H=W=96.
// Round 14: REVERT to round-12 exactly (proven best: 165.08us total, fused
// 96.8us, FETCH/WRITE ideal). r13's all-wave pv rebalance tripled memory
// traffic (32B scattered stores -> L2 partial-line RMW amplification) and is
// abandoned. r12 = r11 structure + cvt_pk_bf16 epilogues + cross-barrier
// weight prefetch + hoisted bias loads.

typedef __attribute__((ext_vector_type(8))) short bh8;   // 8 bf16 = MFMA frag
typedef __attribute__((ext_vector_type(4))) float fx4;   // MFMA 16x16 accum

#define MFMA16(a, b, c) __builtin_amdgcn_mfma_f32_16x16x32_bf16((a), (b), (c), 0, 0, 0)
#define MFMA8(a, b, c) __builtin_amdgcn_mfma_f32_16x16x32_fp8_fp8((a), (b), (c), 0, 0, 0)

__device__ __forceinline__ unsigned short f2bf(float f) {
  unsigned u = __float_as_uint(f);
  u += 0x7fffu + ((u >> 16) & 1u);   // RNE (finite inputs only)
  return (unsigned short)(u >> 16);
}
__device__ __forceinline__ float bf2f(unsigned short u) {
  return __uint_as_float((unsigned)u << 16);
}
// HW packed f32x2 -> bf16x2 (RNE, matches f2bf bit-exact on finite inputs).
__device__ __forceinline__ unsigned cvtpk_bf16(float lo, float hi) {
#if defined(__gfx950__)
  unsigned r;
  asm volatile("v_cvt_pk_bf16_f32 %0, %1, %2" : "=v"(r) : "v"(lo), "v"(hi));
  return r;
#else
  return (unsigned)f2bf(lo) | ((unsigned)f2bf(hi) << 16);
#endif
}
// Software OCP e4m3fn encode (fallback only).
__device__ __forceinline__ unsigned char f2e4m3(float f) {
  unsigned b = __float_as_uint(f);
  unsigned s = (b >> 24) & 0x80u;
  unsigned a = b & 0x7fffffffu;
  float af = __uint_as_float(a);
  if (af >= 448.f) return (unsigned char)(s | 0x7e);
  if (af < 0.015625f) {
    int n = (int)(af * 512.0f + 0.5f);
    return (unsigned char)(s | (unsigned)n);
  }
  a += 0x7ffffu + ((a >> 20) & 1u);
  unsigned E = a >> 23, M = (a >> 20) & 7u;
  if (E >= 136u) return (unsigned char)(s | 0x7e);
  return (unsigned char)(s | ((E - 120u) << 3) | M);
}
#if __has_builtin(__builtin_amdgcn_cvt_pk_fp8_f32)
#define CVTPK8(a, b) __builtin_amdgcn_cvt_pk_fp8_f32((a), (b), 0, false)
#else
#define CVTPK8(a, b) ((int)f2e4m3(a) | ((int)f2e4m3(b) << 8))
#endif

// ---------------- prep: weights fp32 -> bf16, MFMA-A-fragment order in ws ----
__global__ __launch_bounds__(256) void prep_w(const float* __restrict__ Wq,
                                              const float* __restrict__ Wk,
                                              const float* __restrict__ Wv,
                                              short* __restrict__ wf) {
  int tid = blockIdx.x * 256 + threadIdx.x;
  if (tid >= 40960) return;
  int lane = tid & 63;
  int es = (tid >> 6) & 15;
  int gt = tid >> 10;
  int rt = lane & 15;
  int colbase = es * 32 + (lane >> 4) * 8;
  const float* src;
  size_t dst;
  if (gt < 8) {
    int m = gt * 16 + rt;
    src = (m < 64) ? (Wq + (size_t)m * 512) : (Wk + (size_t)(m - 64) * 512);
    dst = (size_t)((gt * 16 + es) * 64 + lane) * 8;
  } else {
    int ct = gt - 8;
    src = Wv + (size_t)(ct * 16 + rt) * 512;
    dst = 65536u + (size_t)((ct * 16 + es) * 64 + lane) * 8;
  }
  bh8 v;
#pragma unroll
  for (int r = 0; r < 8; ++r) v[r] = (short)f2bf(src[colbase + r]);
  *(bh8*)(wf + dst) = v;
}

// ---------------- transpose-in: x[b,c,h,w] f32 -> xT[b,w,h,c] bf16 -----------
__global__ __launch_bounds__(512) void transpose_in(const float* __restrict__ x,
                                                    unsigned short* __restrict__ xT) {
  __shared__ unsigned short L[96 * 132];
  int bi = blockIdx.x;
  int ct = bi & 3;
  int hb = bi >> 2;
  int h = hb % 96;
  int b = hb / 96;
  int tid = threadIdx.x;
  const float* xs = x + ((size_t)(b * 512 + ct * 128) * 96 + h) * 96;
#pragma unroll
  for (int i = 0; i < 12; ++i) {
    int idx = tid + 512 * i;          // 128 cc x 48 w-pairs (float2)
    int cc = idx / 48, wp = idx - cc * 48;
    float2 v = *(const float2*)(xs + (size_t)cc * 9216 + 2 * wp);
    L[(2 * wp) * 132 + cc] = f2bf(v.x);
    L[(2 * wp + 1) * 132 + cc] = f2bf(v.y);
  }
  __syncthreads();
  unsigned short* dst = xT + ((size_t)(b * 96) * 96 + h) * 512 + ct * 128;
#pragma unroll
  for (int i = 0; i < 6; ++i) {
    int idx = tid + 512 * i;          // 96 w x 32 c-quads (8 B)
    int w = idx >> 5, ccq = idx & 31;
    *(ushort4*)(dst + (size_t)w * 49152 + ccq * 4) =
        *(const ushort4*)&L[w * 132 + ccq * 4];
  }
}

// ---------------- un-transpose: out = f32(outT) (residual already folded) ----
__global__ __launch_bounds__(512) void untrans(const unsigned short* __restrict__ oT,
                                               float* __restrict__ out, int b0) {
  __shared__ unsigned short L[128 * 101];
  int bi = blockIdx.x;
  int ct = bi & 3;
  int hb = bi >> 2;
  int h = hb % 96;
  int brel = hb / 96;
  int b = b0 + brel;
  int tid = threadIdx.x;
  const unsigned short* src = oT + ((size_t)(brel * 96) * 96 + h) * 512 + ct * 128;
#pragma unroll
  for (int i = 0; i < 3; ++i) {
    int idx = tid + 512 * i;          // 96 w x 16 c-octs (16 B)
    int w = idx >> 4, ccb = idx & 15;
    bh8 v = *(const bh8*)(src + (size_t)w * 49152 + ccb * 8);
#pragma unroll
    for (int r = 0; r < 8; ++r) L[(ccb * 8 + r) * 101 + w] = (unsigned short)v[r];
  }
  __syncthreads();
  float* os = out + ((size_t)(b * 512 + ct * 128) * 96 + h) * 96;
#pragma unroll
  for (int i = 0; i < 12; ++i) {
    int idx = tid + 512 * i;          // 128 cc x 48 w-pairs (float2 stores)
    int cc = idx / 48, wp = idx - cc * 48;
    float2 v;
    v.x = bf2f(L[cc * 101 + 2 * wp]);
    v.y = bf2f(L[cc * 101 + 2 * wp + 1]);
    *(float2*)(os + (size_t)cc * 9216 + 2 * wp) = v;
  }
}

// ---------------- main fused kernel (round 14 = round 12): one wg per (b,w) --
// LDS map (bytes), 157440 total — 1024 threads (16 waves, 4 waves/SIMD):
//   X    [96][512] bf16, pitch 1024, XOR swizzle byte^=((j&7)<<4)  0      .. 98304
//   Q    [96][64]  bf16, pitch 128, XOR swizzle                    98304  .. 110592
//   K    [96][64]  bf16, pitch 128, XOR swizzle                    110592 .. 122880
//   ATT8 [96][104] fp8                                             122880 .. 132864
//   V8A  [256][96] fp8, row-XOR swizzle ((row>>2)&3)<<3            132864 .. 157440
//   V8B  [256][96] fp8 — aliases Q/K (dead after softmax)          98304  .. 122880
// X stays live to the end (residual source for the epilogue).
#define XO5 0
#define QO5 98304
#define KO5 110592
#define AT5 122880
#define V5A 132864
#define V5B 98304
#define SMEM5 157440

__global__ __launch_bounds__(1024, 4) void cc_fused11(
    const float* __restrict__ bq, const float* __restrict__ bk,
    const float* __restrict__ bv, const float* __restrict__ gamma,
    const short* __restrict__ wf, const unsigned short* __restrict__ xT,
    unsigned short* __restrict__ outTm, unsigned short* __restrict__ outT7) {
  extern __shared__ char smem[];
  const int tid = threadIdx.x;
  const int l = tid & 63, wv = tid >> 6;          // wv in [0,16)
  const int rl = l & 15, kg = l >> 4;
  const int bid = blockIdx.x;
  const float g0 = gamma[0];
  const unsigned short* xrow = xT + (size_t)bid * 49152;
  const short* wvb = wf + 65536;

  unsigned short* obase = (bid < 672)
      ? (outTm + (size_t)bid * 49152)
      : (outT7 + (size_t)(bid - 672) * 49152);

  // ---- vblk4: 256-ch block cb -> V8 fp8; 4mt x 3nt; es=0 frags preloaded ----
  auto vblk4 = [&](int cb, int vo, int mg4, int ng4, bh8 c0, bh8 c1, bh8 c2, bh8 c3) {
    const int mtb = mg4 * 4;
    fx4 vac[4][3] = {};
    bh8 ac[4] = {c0, c1, c2, c3};
#pragma unroll 2
    for (int es = 0; es < 16; ++es) {
      int esn = (es < 15) ? es + 1 : 15;
      bh8 an[4];
#pragma unroll
      for (int q = 0; q < 4; ++q)
        an[q] = *(const bh8*)(wvb + (((cb * 16 + mtb + q) * 16 + esn) * 64 + l) * 8);
      int kb = es * 64 + kg * 16;
      __builtin_amdgcn_s_setprio(1);
#pragma unroll
      for (int t = 0; t < 3; ++t) {
        int j = (3 * ng4 + t) * 16 + rl;
        bh8 bx = *(const bh8*)(smem + XO5 + j * 1024 + (kb ^ ((j & 7) << 4)));
#pragma unroll
        for (int q = 0; q < 4; ++q) vac[q][t] = MFMA16(ac[q], bx, vac[q][t]);
      }
      __builtin_amdgcn_s_setprio(0);
#pragma unroll
      for (int q = 0; q < 4; ++q) ac[q] = an[q];
    }
#pragma unroll
    for (int q = 0; q < 4; ++q)
#pragma unroll
      for (int r = 0; r < 4; ++r) {
        int row = (mtb + q) * 16 + kg * 4 + r;
        int sz = ((row >> 2) & 3) << 3;
        int a = row * 96 + ng4 * 48 + rl;
        unsigned char* vp = (unsigned char*)smem + vo;
        int p01 = CVTPK8(vac[q][0][r], vac[q][1][r]);
        int p22 = CVTPK8(vac[q][2][r], vac[q][2][r]);
        vp[a ^ sz] = (unsigned char)p01;
        vp[(a + 16) ^ sz] = (unsigned char)(p01 >> 8);
        vp[(a + 32) ^ sz] = (unsigned char)p22;
      }
  };

  // ---- vblk2: 2mt x 3nt, all 16 waves; es=0 frags preloaded ----
  auto vblk2 = [&](int cb, int vo, bh8 c0, bh8 c1) {
    const int mg = wv >> 1, ng = wv & 1;
    const int mtb = mg * 2;
    fx4 vac[2][3] = {};
    bh8 ac[2] = {c0, c1};
#pragma unroll 2
    for (int es = 0; es < 16; ++es) {
      int esn = (es < 15) ? es + 1 : 15;
      bh8 an[2];
#pragma unroll
      for (int q = 0; q < 2; ++q)
        an[q] = *(const bh8*)(wvb + (((cb * 16 + mtb + q) * 16 + esn) * 64 + l) * 8);
      int kb = es * 64 + kg * 16;
      __builtin_amdgcn_s_setprio(1);
#pragma unroll
      for (int t = 0; t < 3; ++t) {
        int j = (3 * ng + t) * 16 + rl;
        bh8 bx = *(const bh8*)(smem + XO5 + j * 1024 + (kb ^ ((j & 7) << 4)));
        vac[0][t] = MFMA16(ac[0], bx, vac[0][t]);
        vac[1][t] = MFMA16(ac[1], bx, vac[1][t]);
      }
      __builtin_amdgcn_s_setprio(0);
      ac[0] = an[0];
      ac[1] = an[1];
    }
#pragma unroll
    for (int q = 0; q < 2; ++q)
#pragma unroll
      for (int r = 0; r < 4; ++r) {
        int row = (mtb + q) * 16 + kg * 4 + r;
        int sz = ((row >> 2) & 3) << 3;
        int a = row * 96 + ng * 48 + rl;
        unsigned char* vp = (unsigned char*)smem + vo;
        int p01 = CVTPK8(vac[q][0][r], vac[q][1][r]);
        int p22 = CVTPK8(vac[q][2][r], vac[q][2][r]);
        vp[a ^ sz] = (unsigned char)p01;
        vp[(a + 16) ^ sz] = (unsigned char)(p01 >> 8);
        vp[(a + 32) ^ sz] = (unsigned char)p22;
      }
  };

  // ---- pv: waves 0..11, 1 i-tile x 8 c-tiles; cvt_pk epilogue ----
  auto pv = [&](int cb, int vo) {
    const int it = wv >> 1, ch = wv & 1;          // it in [0,6), ch in [0,2)
    fx4 pac[8] = {};
    __builtin_amdgcn_s_setprio(1);
#pragma unroll
    for (int ks = 0; ks < 3; ++ks) {
      long aa = *(const long*)(smem + AT5 + (it * 16 + rl) * 104 + ks * 32 + kg * 8);
      long bb[8];
#pragma unroll
      for (int u = 0; u < 8; ++u) {
        int row = (ch * 8 + u) * 16 + rl;
        bb[u] = *(const long*)(smem + vo +
                               ((row * 96 + ks * 32 + kg * 8) ^ (((row >> 2) & 3) << 3)));
      }
#pragma unroll
      for (int u = 0; u < 8; ++u) pac[u] = MFMA8(aa, bb[u], pac[u]);
    }
    __builtin_amdgcn_s_setprio(0);
    const int i0 = it * 16 + kg * 4;
#pragma unroll
    for (int u = 0; u < 8; ++u) {
      int c = cb * 256 + (ch * 8 + u) * 16 + rl;
      float gb = g0 * bv[c];    // softmax rows sum to 1 -> v-bias adds directly
      float o[4];
#pragma unroll
      for (int r = 0; r < 4; ++r) {
        unsigned short xv = *(const unsigned short*)(
            smem + XO5 + (i0 + r) * 1024 + ((2 * c) ^ (((i0 + r) & 7) << 4)));
        o[r] = fmaf(g0, pac[u][r], gb + bf2f(xv));
      }
      unsigned pk01 = cvtpk_bf16(o[0], o[1]);
      unsigned pk23 = cvtpk_bf16(o[2], o[3]);
      obase[(size_t)(i0 + 0) * 512 + c] = (unsigned short)pk01;
      obase[(size_t)(i0 + 1) * 512 + c] = (unsigned short)(pk01 >> 16);
      obase[(size_t)(i0 + 2) * 512 + c] = (unsigned short)pk23;
      obase[(size_t)(i0 + 3) * 512 + c] = (unsigned short)(pk23 >> 16);
    }
  };

  // ---- P0: X[j][c] into LDS as bf16 (swizzled), coalesced from xT ----
#pragma unroll
  for (int i = 0; i < 6; ++i) {
    int idx = tid + 1024 * i;       // 96 j x 64 16B-chunks
    int j = idx >> 6, cbk = idx & 63;
    bh8 v = *(const bh8*)(xrow + (size_t)j * 512 + cbk * 8);
    *(bh8*)(smem + XO5 + j * 1024 + ((cbk * 16) ^ ((j & 7) << 4))) = v;
  }
  // cross-barrier prefetch: P1's es=0 weight frag (latency hides under barrier)
  const int mgq = wv >> 1, ngq = wv & 1;          // P1 role: mg in [0,8)
  bh8 p1a = *(const bh8*)(wf + ((mgq * 16 + 0) * 64 + l) * 8);
  __syncthreads();

  // ---- P1: [q;k] = [Wq;Wk] @ X, 1mt x 3nt per wave, +1-ahead A prefetch ----
  {
    fx4 acc[3] = {};
    bh8 a0c = p1a;
#pragma unroll 2
    for (int es = 0; es < 16; ++es) {
      int esn = (es < 15) ? es + 1 : 15;
      bh8 a0n = *(const bh8*)(wf + ((mgq * 16 + esn) * 64 + l) * 8);
      int kb = es * 64 + kg * 16;
      __builtin_amdgcn_s_setprio(1);
#pragma unroll
      for (int t = 0; t < 3; ++t) {
        int j = (3 * ngq + t) * 16 + rl;
        bh8 bx = *(const bh8*)(smem + XO5 + j * 1024 + (kb ^ ((j & 7) << 4)));
        acc[t] = MFMA16(a0c, bx, acc[t]);
      }
      __builtin_amdgcn_s_setprio(0);
      a0c = a0n;
    }
    {
      int base = mgq * 16;
      const float* bp = (base < 64) ? bq : bk;
      const int qko = (base < 64) ? QO5 : KO5;
      const int ml0 = (base & 63) + kg * 4;
      float b0 = bp[ml0], b1 = bp[ml0 + 1], b2 = bp[ml0 + 2], b3 = bp[ml0 + 3];
#pragma unroll
      for (int t = 0; t < 3; ++t) {
        int i = (3 * ngq + t) * 16 + rl;
        unsigned pk01 = cvtpk_bf16(acc[t][0] + b0, acc[t][1] + b1);
        unsigned pk23 = cvtpk_bf16(acc[t][2] + b2, acc[t][3] + b3);
        int swz = (i & 7) << 4;
        *(unsigned*)(smem + qko + i * 128 + ((ml0 * 2) ^ swz)) = pk01;
        *(unsigned*)(smem + qko + i * 128 + ((ml0 * 2 + 4) ^ swz)) = pk23;
      }
    }
  }
  // cross-barrier prefetch: vblk0's es=0 frags for waves 8..15
  bh8 h0, h1, h2, h3;
  if (wv >= 8) {
    int mtb = ((wv - 8) >> 1) * 4;
    h0 = *(const bh8*)(wvb + (((mtb + 0) * 16 + 0) * 64 + l) * 8);
    h1 = *(const bh8*)(wvb + (((mtb + 1) * 16 + 0) * 64 + l) * 8);
    h2 = *(const bh8*)(wvb + (((mtb + 2) * 16 + 0) * 64 + l) * 8);
    h3 = *(const bh8*)(wvb + (((mtb + 3) * 16 + 0) * 64 + l) * 8);
  }
  __syncthreads();

  // ---- Phase A: waves 0-5 softmax ONLY || waves 8-15 vblk0 -> V5A ----
  if (wv < 6) {
    const int i0 = wv * 16;
    fx4 e[6] = {};
#pragma unroll
    for (int ks = 0; ks < 2; ++ks) {
      int kb = (ks * 32 + kg * 8) * 2;
      int ia = i0 + rl;
      bh8 aq = *(const bh8*)(smem + QO5 + ia * 128 + (kb ^ ((ia & 7) << 4)));
#pragma unroll
      for (int jt = 0; jt < 6; ++jt) {
        int j = jt * 16 + rl;
        bh8 bkf = *(const bh8*)(smem + KO5 + j * 128 + (kb ^ ((j & 7) << 4)));
        e[jt] = MFMA16(aq, bkf, e[jt]);
      }
    }
#pragma unroll
    for (int r = 0; r < 4; ++r) {
      float mx = e[0][r];
#pragma unroll
      for (int jt = 1; jt < 6; ++jt) mx = fmaxf(mx, e[jt][r]);
      mx = fmaxf(mx, __shfl_xor(mx, 1));
      mx = fmaxf(mx, __shfl_xor(mx, 2));
      mx = fmaxf(mx, __shfl_xor(mx, 4));
      mx = fmaxf(mx, __shfl_xor(mx, 8));
      float pp[6], s = 0.f;
#pragma unroll
      for (int jt = 0; jt < 6; ++jt) { pp[jt] = __expf(e[jt][r] - mx); s += pp[jt]; }
      s += __shfl_xor(s, 1);
      s += __shfl_xor(s, 2);
      s += __shfl_xor(s, 4);
      s += __shfl_xor(s, 8);
      float inv = 1.0f / s;
      int i = i0 + kg * 4 + r;
      unsigned char* arow = (unsigned char*)smem + AT5 + i * 104 + rl;
      int p01 = CVTPK8(pp[0] * inv, pp[1] * inv);
      int p23 = CVTPK8(pp[2] * inv, pp[3] * inv);
      int p45 = CVTPK8(pp[4] * inv, pp[5] * inv);
      arow[0] = (unsigned char)p01;
      arow[16] = (unsigned char)(p01 >> 8);
      arow[32] = (unsigned char)p23;
      arow[48] = (unsigned char)(p23 >> 8);
      arow[64] = (unsigned char)p45;
      arow[80] = (unsigned char)(p45 >> 8);
    }
  } else if (wv >= 8) {
    vblk4(0, V5A, (wv - 8) >> 1, wv & 1, h0, h1, h2, h3);
  }
  // cross-barrier prefetch: vblk1's es=0 frags (all waves)
  bh8 w20, w21;
  {
    int mtb2 = (wv >> 1) * 2;
    w20 = *(const bh8*)(wvb + (((16 + mtb2 + 0) * 16 + 0) * 64 + l) * 8);
    w21 = *(const bh8*)(wvb + (((16 + mtb2 + 1) * 16 + 0) * 64 + l) * 8);
  }
  __syncthreads();

  // ---- Phase B: pv0 (waves 0-11) then vblk1 -> V5B (all 16 waves).
  //      Waves 12-15 skip pv and start vblk1 early. ----
  if (wv < 12) pv(0, V5A);
  vblk2(1, V5B, w20, w21);
  __syncthreads();

  // ---- Phase C: pv1 (waves 0-11) ----
  if (wv < 12) pv(1, V5B);
}

// ---------------- legacy self-contained fallback (round-1 proven) ------------
__global__ __launch_bounds__(512, 2) void cc_fused_legacy(
    const float* __restrict__ x, const float* __restrict__ bq,
    const float* __restrict__ bk, const float* __restrict__ bv,
    const float* __restrict__ gamma, const short* __restrict__ wf,
    float* __restrict__ out) {
  extern __shared__ char smem[];
  const int tid = threadIdx.x;
  const int l = tid & 63, wv = tid >> 6;
  const int rl = l & 15, kg = l >> 4;
  const int bid = blockIdx.x;
  const int b = (bid >> 3) / 12;
  const int w = (bid & 7) * 12 + ((bid >> 3) % 12);
  const float g0 = gamma[0];
  const float* xb = x + (size_t)b * 4718592 + w;
  for (int idx = tid; idx < 24576; idx += 512) {
    int j = idx >> 8;
    int c = (idx & 255) * 2;
    float a0 = xb[(size_t)c * 9216 + j * 96];
    float a1 = xb[(size_t)(c + 1) * 9216 + j * 96];
    unsigned pk = (unsigned)f2bf(a0) | ((unsigned)f2bf(a1) << 16);
    *(unsigned*)(smem + j * 1024 + ((c * 2) ^ ((j & 7) << 4))) = pk;
  }
  __syncthreads();
  {
    fx4 acc[6] = {};
    for (int es = 0; es < 16; ++es) {
      bh8 a = *(const bh8*)(wf + ((wv * 16 + es) * 64 + l) * 8);
      int kb = (es * 32 + kg * 8) * 2;
#pragma unroll
      for (int nt = 0; nt < 6; ++nt) {
        int j = nt * 16 + rl;
        bh8 bx = *(const bh8*)(smem + j * 1024 + (kb ^ ((j & 7) << 4)));
        acc[nt] = MFMA16(a, bx, acc[nt]);
      }
    }
    const float* bp = (wv < 4) ? bq : bk;
    const int qko = (wv < 4) ? 118272 : 130560;
    const int mb = (wv * 16) & 63;
#pragma unroll
    for (int r = 0; r < 4; ++r) {
      int ml = mb + kg * 4 + r;
      float bias = bp[ml];
#pragma unroll
      for (int nt = 0; nt < 6; ++nt) {
        int i = nt * 16 + rl;
        *(unsigned short*)(smem + qko + i * 128 + ((ml * 2) ^ ((i & 7) << 4))) =
            f2bf(acc[nt][r] + bias);
      }
    }
  }
  __syncthreads();
  if (wv < 6) {
    const int i0 = wv * 16;
    fx4 e[6] = {};
#pragma unroll
    for (int ks = 0; ks < 2; ++ks) {
      int kb = (ks * 32 + kg * 8) * 2;
      int ia = i0 + rl;
      bh8 aq = *(const bh8*)(smem + 118272 + ia * 128 + (kb ^ ((ia & 7) << 4)));
#pragma unroll
      for (int jt = 0; jt < 6; ++jt) {
        int j = jt * 16 + rl;
        bh8 bkf = *(const bh8*)(smem + 130560 + j * 128 + (kb ^ ((j & 7) << 4)));
        e[jt] = MFMA16(aq, bkf, e[jt]);
      }
    }
#pragma unroll
    for (int r = 0; r < 4; ++r) {
      float mx = e[0][r];
#pragma unroll
      for (int jt = 1; jt < 6; ++jt) mx = fmaxf(mx, e[jt][r]);
      mx = fmaxf(mx, __shfl_xor(mx, 1));
      mx = fmaxf(mx, __shfl_xor(mx, 2));
      mx = fmaxf(mx, __shfl_xor(mx, 4));
      mx = fmaxf(mx, __shfl_xor(mx, 8));
      float p[6], s = 0.f;
#pragma unroll
      for (int jt = 0; jt < 6; ++jt) { p[jt] = __expf(e[jt][r] - mx); s += p[jt]; }
      s += __shfl_xor(s, 1);
      s += __shfl_xor(s, 2);
      s += __shfl_xor(s, 4);
      s += __shfl_xor(s, 8);
      float inv = 1.0f / s;
      int i = i0 + kg * 4 + r;
#pragma unroll
      for (int jt = 0; jt < 6; ++jt) {
        int j = jt * 16 + rl;
        *(unsigned short*)(smem + 98304 + i * 208 + 2 * j) = f2bf(p[jt] * inv);
      }
    }
  }
  __syncthreads();
  for (int cb = 0; cb < 8; ++cb) {
    {
      const int mt = wv >> 1, ntb = (wv & 1) * 3;
      fx4 acc[3] = {};
      for (int es = 0; es < 16; ++es) {
        bh8 a = *(const bh8*)(wf + 65536 + (((cb * 4 + mt) * 16 + es) * 64 + l) * 8);
        int kb = (es * 32 + kg * 8) * 2;
#pragma unroll
        for (int t = 0; t < 3; ++t) {
          int j = (ntb + t) * 16 + rl;
          bh8 bx = *(const bh8*)(smem + j * 1024 + (kb ^ ((j & 7) << 4)));
          acc[t] = MFMA16(a, bx, acc[t]);
        }
      }
#pragma unroll
      for (int t = 0; t < 3; ++t) {
        int j = (ntb + t) * 16 + rl;
#pragma unroll
        for (int r = 0; r < 4; ++r) {
          int cl = mt * 16 + kg * 4 + r;
          *(unsigned short*)(smem + 118272 + cl * 208 + 2 * j) = f2bf(acc[t][r]);
        }
      }
    }
    __syncthreads();
    {
      fx4 acc[3] = {};
      const int tg0 = wv * 3;
#pragma unroll
      for (int ks = 0; ks < 3; ++ks) {
        int jb = (ks * 32 + kg * 8) * 2;
#pragma unroll
        for (int s = 0; s < 3; ++s) {
          int it = (tg0 + s) >> 2, ct = (tg0 + s) & 3;
          bh8 a = *(const bh8*)(smem + 98304 + (it * 16 + rl) * 208 + jb);
          bh8 bvv = *(const bh8*)(smem + 118272 + (ct * 16 + rl) * 208 + jb);
          acc[s] = MFMA16(a, bvv, acc[s]);
        }
      }
#pragma unroll
      for (int s = 0; s < 3; ++s) {
        int it = (tg0 + s) >> 2, ct = (tg0 + s) & 3;
        int c = cb * 64 + ct * 16 + rl;
        float bvc = bv[c];
        size_t base = (size_t)(b * 512 + c) * 9216 + w;
#pragma unroll
        for (int r = 0; r < 4; ++r) {
          int i = it * 16 + kg * 4 + r;
          size_t g = base + (size_t)i * 96;
          out[g] = g0 * (acc[s][r] + bvc) + x[g];
        }
      }
    }
    __syncthreads();
  }
}

extern "C" void kernel_launch(void* const* d_in, const int* in_sizes, int n_in,
                              void* d_out, int out_size, void* d_ws, size_t ws_size,
                              hipStream_t stream) {
  const float* x = (const float*)d_in[0];
  const float* Wq = (const float*)d_in[1];
  const float* bq = (const float*)d_in[2];
  const float* Wk = (const float*)d_in[3];
  const float* bk = (const float*)d_in[4];
  const float* Wv = (const float*)d_in[5];
  const float* bv = (const float*)d_in[6];
  const float* gamma = (const float*)d_in[7];
  float* out = (float*)d_out;
  short* wf = (short*)d_ws;                    // 655,360 B weights at ws+0

  prep_w<<<160, 256, 0, stream>>>(Wq, Wk, Wv, wf);

  const size_t WS_SMALL = 1048576u + 9437184u;           // outT(b=7) only in ws
  const size_t WS_BIG = 1048576u + 75497472u;            // ALL of outT in ws

  if (ws_size >= WS_SMALL) {
    unsigned short* xT = (unsigned short*)d_out;         // 75.5 MB, dead after fused

    hipFuncSetAttribute((const void*)cc_fused11,
                        hipFuncAttributeMaxDynamicSharedMemorySize, SMEM5);
    transpose_in<<<3072, 512, 0, stream>>>(x, xT);

    if (ws_size >= WS_BIG) {
      // All of outT in ws: no out/outT overlap, single un-transpose launch.
      unsigned short* outTall = (unsigned short*)((char*)d_ws + 1048576);
      cc_fused11<<<768, 1024, SMEM5, stream>>>(bq, bk, bv, gamma, (const short*)wf,
                                               xT, outTall,
                                               outTall + (size_t)672 * 49152);
      untrans<<<3072, 512, 0, stream>>>(outTall, out, 0);              // b0..7
    } else {
      unsigned short* outTm = (unsigned short*)((char*)d_out + 75497472);  // b0..6
      unsigned short* outT7 = (unsigned short*)((char*)d_ws + 1048576);    // b7
      cc_fused11<<<768, 1024, SMEM5, stream>>>(bq, bk, bv, gamma, (const short*)wf,
                                               xT, outTm, outT7);
      // Ordered un-transpose passes: each launch only overwrites outT regions
      // consumed by the previous launch (range proof per round 2; xT dead).
      untrans<<<1536, 512, 0, stream>>>(outTm, out, 0);                       // b0..3
      untrans<<<768, 512, 0, stream>>>(outTm + (size_t)4 * 4718592, out, 4);  // b4,5
      untrans<<<384, 512, 0, stream>>>(outTm + (size_t)6 * 4718592, out, 6);  // b6
      untrans<<<384, 512, 0, stream>>>(outT7, out, 7);                        // b7
    }
  } else {
    hipFuncSetAttribute((const void*)cc_fused_legacy,
                        hipFuncAttributeMaxDynamicSharedMemorySize, 142848);
    cc_fused_legacy<<<768, 512, 142848, stream>>>(x, bq, bk, bv, gamma,
                                                  (const short*)wf, out);
  }
}